// Round 15
// baseline (159.370 us; speedup 1.0000x reference)
//
#include <hip/hip_runtime.h>
#include <hip/hip_bf16.h>

#define NQ   14
#define DIM  16384      // 2^14
#define BLK  1024
#define WMUL 0.6324555320336759f  // sqrt(2/5)

typedef float v2f __attribute__((ext_vector_type(2)));

struct C2 { float x, y; };  // build-time only
__device__ inline C2 cmulc(C2 a, C2 b){ return C2{a.x*b.x - a.y*b.y, a.x*b.y + a.y*b.x}; }
__device__ inline C2 caddc(C2 a, C2 b){ return C2{a.x+b.x, a.y+b.y}; }
__device__ inline void mm2(const C2* a, const C2* b, C2* o) {
    o[0] = caddc(cmulc(a[0],b[0]), cmulc(a[1],b[2]));
    o[1] = caddc(cmulc(a[0],b[1]), cmulc(a[1],b[3]));
    o[2] = caddc(cmulc(a[2],b[0]), cmulc(a[3],b[2]));
    o[3] = caddc(cmulc(a[2],b[1]), cmulc(a[3],b[3]));
}
__device__ inline void build_gate(int ty, float t, C2* g) {
    float sn, cs;
    __sincosf(0.5f * t, &sn, &cs);
    if (ty == 0) {        // rx
        g[0] = C2{cs, 0.f}; g[1] = C2{0.f, -sn};
        g[2] = C2{0.f, -sn}; g[3] = C2{cs, 0.f};
    } else if (ty == 1) { // ry
        g[0] = C2{cs, 0.f}; g[1] = C2{-sn, 0.f};
        g[2] = C2{sn, 0.f}; g[3] = C2{cs, 0.f};
    } else {              // rz
        g[0] = C2{cs, -sn}; g[1] = C2{0.f, 0.f};
        g[2] = C2{0.f, 0.f}; g[3] = C2{cs, sn};
    }
}
__device__ const int TYPES[5][3] = {
    {0,1,2},  // XYZ
    {1,2,1},  // YZY
    {2,1,0},  // ZYX
    {0,2,0},  // XZX
    {1,2,1},  // YZY
};

// bank-conflict swizzle; GF(2)-LINEAR: slotf(a|b) = slotf(a)^slotf(b) for disjoint a,b
__device__ inline constexpr uint32_t slotf(uint32_t i){
    return i ^ (((i>>4) ^ (i>>8) ^ (i>>12)) & 15u);
}
template<int B> __device__ inline uint32_t ins0(uint32_t t){
    return ((t & ~((1u<<B)-1u)) << 1) | (t & ((1u<<B)-1u));
}
template<int B0,int B1,int B2> __device__ inline uint32_t expand3(uint32_t t){
    return ins0<B2>(ins0<B1>(ins0<B0>(t)));
}
template<int B0,int B1,int B2> __device__ inline constexpr uint32_t rmask3(int r){
    return ((r&1)?(1u<<B0):0u) | ((r&2)?(1u<<B1):0u) | ((r&4)?(1u<<B2):0u);
}

#define SBAR __builtin_amdgcn_sched_barrier(0)

// SU(2) packed rotation on local bit J over v[16] (both slabs, 8 indep pairs).
// Gate storage: 4 v2f {A1,A2,B1,B2}: A1=(a.x,a.x) A2=(-a.y,a.y) B1=(b.x,b.x)
// B2=(-b.y,b.y) for M=[[a,b],[-conj(b),conj(a)]].
// y0 = A1*x0 + A2*s0 + B1*x1 + B2*s1 ; y1 = A1*x1 - A2*s1 - B1*x0 + B2*s0
template<int J>
__device__ inline void rotD(v2f* v, const v2f* __restrict__ g){
    const v2f A1=g[0], A2=g[1], B1=g[2], B2=g[3];
    #pragma unroll
    for (int r = 0; r < 16; ++r){
        if (!(r & (1 << J))) {          // J<3: pairs stay within each half
            v2f x0 = v[r], x1 = v[r | (1 << J)];
            v2f s0 = x0.yx, s1 = x1.yx;
            v2f y0 = A1*x0 + A2*s0 + B1*x1 + B2*s1;
            v2f y1 = A1*x1 - A2*s1 - B1*x0 + B2*s0;
            v[r] = y0; v[r | (1<<J)] = y1;
        }
    }
}
// CNOT both-in-reg (register renaming, free); C,T < 3 so both halves ok
template<int C, int T>
__device__ inline void cnot16(v2f* v){
    #pragma unroll
    for (int r = 0; r < 16; ++r){
        if ((r & (1 << C)) && !(r & (1 << T))) {
            v2f tt = v[r]; v[r] = v[r | (1 << T)]; v[r | (1 << T)] = tt;
        }
    }
}
// CNOT with control = thread-index bit (<b10, same both slabs), target reg bit T
template<int T>
__device__ inline void cnotSel16(v2f* v, bool c){
    #pragma unroll
    for (int r = 0; r < 16; ++r){
        if (!(r & (1 << T))) {
            v2f lo = v[r], hi = v[r | (1 << T)];
            v[r]          = c ? hi : lo;
            v[r | (1<<T)] = c ? lo : hi;
        }
    }
}

__global__ __launch_bounds__(BLK) void qsim_kernel(
        const float* __restrict__ xr, const float* __restrict__ xi,
        const float* __restrict__ w, float* __restrict__ out) {
    __shared__ v2f s[DIM];            // 128 KiB statevector (swizzled layout)
    __shared__ v2f gmp[5 * NQ * 4];   // 70 gates, SU(2) form (2.2 KiB)
    __shared__ float meas[4];         // absorbed-L5 observable: alpha, beta, p, q
    __shared__ float red[BLK / 64];

    const int b   = blockIdx.x;
    const uint32_t tid = threadIdx.x;

    // ---- build fused gate matrices (threads 0..69), store SU(2) packed form ----
    if (tid < 5 * NQ) {
        const int li = tid / NQ, q = tid % NQ;
        C2 M[4], G[4], T[4];
        #pragma unroll
        for (int j = 0; j < 3; ++j) {
            float t = w[3 * NQ * li + 3 * q + j] * WMUL;
            build_gate(TYPES[li][j], t, G);
            if (j == 0) { M[0]=G[0]; M[1]=G[1]; M[2]=G[2]; M[3]=G[3]; }
            else { mm2(G, M, T); M[0]=T[0]; M[1]=T[1]; M[2]=T[2]; M[3]=T[3]; }
        }
        v2f* gb = &gmp[tid * 4];
        gb[0] = v2f{ M[0].x, M[0].x};  // A1
        gb[1] = v2f{-M[0].y, M[0].y};  // A2
        gb[2] = v2f{ M[1].x, M[1].x};  // B1
        gb[3] = v2f{-M[1].y, M[1].y};  // B2
        // absorbed observable M1 = M† Z M for the layer-5 qubit-0 rotation
        if (tid == 4 * NQ + 0) {
            meas[0] = M[0].x*M[0].x + M[0].y*M[0].y - (M[2].x*M[2].x + M[2].y*M[2].y);
            meas[1] = M[1].x*M[1].x + M[1].y*M[1].y - (M[3].x*M[3].x + M[3].y*M[3].y);
            meas[2] = (M[0].x*M[1].x + M[0].y*M[1].y) - (M[2].x*M[3].x + M[2].y*M[3].y);
            meas[3] = (M[0].x*M[1].y - M[0].y*M[1].x) - (M[2].x*M[3].y - M[2].y*M[3].x);
        }
    }
    __syncthreads();

    const float* xrb = xr + (size_t)b * DIM;
    const float* xib = xi + (size_t)b * DIM;

    // qubit q <-> bit (13-q).
    #define GMP(li, q) (&gmp[((li) * NQ + (q)) * 4])

    // One pass: BOTH slabs in one sweep: v[0..7] = slab0, v[8..15] = slab1.
    #define PASS(X0, X1, X2, ...)                                                  \
        {                                                                          \
            const uint32_t sb0 = slotf(expand3<X0,X1,X2>(tid));                    \
            const uint32_t sb1 = slotf(expand3<X0,X1,X2>(tid + BLK));              \
            v2f v[16];                                                             \
            _Pragma("unroll")                                                      \
            for (int r = 0; r < 8; ++r) {                                          \
                v[r]     = s[sb0 ^ slotf(rmask3<X0,X1,X2>(r))];                    \
                v[r + 8] = s[sb1 ^ slotf(rmask3<X0,X1,X2>(r))];                    \
            }                                                                      \
            __VA_ARGS__                                                            \
            _Pragma("unroll")                                                      \
            for (int r = 0; r < 8; ++r) {                                          \
                s[sb0 ^ slotf(rmask3<X0,X1,X2>(r))] = v[r];                        \
                s[sb1 ^ slotf(rmask3<X0,X1,X2>(r))] = v[r + 8];                    \
            }                                                                      \
        }                                                                          \
        __syncthreads();

    float local = 0.f;

    // ---- 4 ring layers, 5 non-overlapping windows each; L5 absorbed in meas[] ----
    // A(11,12,13): rot q0,q1,q2 + CN(0,1),(1,2)
    // B(8,9,10):   rot q3,q4,q5 + CN(2,3)[sel ctl=t8] + CN(3,4),(4,5)
    // C(5,6,7):    rot q6,q7,q8 + CN(5,6)[sel ctl=t5] + CN(6,7),(7,8)
    // D(2,3,4):    rot q9,q10,q11 + CN(8,9)[sel ctl=t2] + CN(9,10),(10,11)
    // E(0,1,13):   rot q12,q13 + CN(11,12)[sel ctl=t0] + CN(12,13),(13,0)
    //              (li==3: fuse M1 quadratic form on b13 = L2 pairs, no scatter)
    #pragma unroll 1
    for (int li = 0; li < 4; ++li) {
        // ---- A (11,12,13) ----
        {
            const uint32_t sb0 = slotf(expand3<11,12,13>(tid));
            const uint32_t sb1 = slotf(expand3<11,12,13>(tid + BLK));
            v2f v[16];
            if (li == 0) {
                #pragma unroll
                for (int r = 0; r < 16; ++r) {
                    uint32_t t = tid + (uint32_t)(r >> 3) * BLK;
                    uint32_t i = t | ((uint32_t)(r & 7) << 11);  // expand3<11,12,13>(t)=t
                    v[r] = v2f{xrb[i], xib[i]};
                }
            } else {
                #pragma unroll
                for (int r = 0; r < 8; ++r) {
                    v[r]     = s[sb0 ^ slotf(rmask3<11,12,13>(r))];
                    v[r + 8] = s[sb1 ^ slotf(rmask3<11,12,13>(r))];
                }
            }
            rotD<2>(v, GMP(li,0)); SBAR;
            rotD<1>(v, GMP(li,1)); SBAR;
            rotD<0>(v, GMP(li,2));
            cnot16<2,1>(v); cnot16<1,0>(v);                // CN(0,1),(1,2)
            #pragma unroll
            for (int r = 0; r < 8; ++r) {
                s[sb0 ^ slotf(rmask3<11,12,13>(r))] = v[r];
                s[sb1 ^ slotf(rmask3<11,12,13>(r))] = v[r + 8];
            }
        }
        __syncthreads();

        // ---- B (8,9,10): rot q3(b10),q4(b9),q5(b8) ----
        PASS(8,9,10,
            rotD<2>(v, GMP(li,3)); SBAR;
            rotD<1>(v, GMP(li,4)); SBAR;
            rotD<0>(v, GMP(li,5));
            cnotSel16<2>(v, (tid >> 8) & 1u);              // CN(2,3): ctl q2=b11
            cnot16<2,1>(v); cnot16<1,0>(v);                // CN(3,4),(4,5)
        )
        // ---- C (5,6,7): rot q6(b7),q7(b6),q8(b5) ----
        PASS(5,6,7,
            rotD<2>(v, GMP(li,6)); SBAR;
            rotD<1>(v, GMP(li,7)); SBAR;
            rotD<0>(v, GMP(li,8));
            cnotSel16<2>(v, (tid >> 5) & 1u);              // CN(5,6): ctl q5=b8
            cnot16<2,1>(v); cnot16<1,0>(v);                // CN(6,7),(7,8)
        )
        // ---- D (2,3,4): rot q9(b4),q10(b3),q11(b2) ----
        PASS(2,3,4,
            rotD<2>(v, GMP(li,9)); SBAR;
            rotD<1>(v, GMP(li,10)); SBAR;
            rotD<0>(v, GMP(li,11));
            cnotSel16<2>(v, (tid >> 2) & 1u);              // CN(8,9): ctl q8=b5
            cnot16<2,1>(v); cnot16<1,0>(v);                // CN(9,10),(10,11)
        )
        // ---- E (0,1,13): rot q12(b1=L1),q13(b0=L0) ----
        {
            const uint32_t sb0 = slotf(expand3<0,1,13>(tid));
            const uint32_t sb1 = slotf(expand3<0,1,13>(tid + BLK));
            v2f v[16];
            #pragma unroll
            for (int r = 0; r < 8; ++r) {
                v[r]     = s[sb0 ^ slotf(rmask3<0,1,13>(r))];
                v[r + 8] = s[sb1 ^ slotf(rmask3<0,1,13>(r))];
            }
            rotD<1>(v, GMP(li,12)); SBAR;
            rotD<0>(v, GMP(li,13));
            cnotSel16<1>(v, tid & 1u);                     // CN(11,12): ctl q11=b2
            cnot16<1,0>(v);                                // CN(12,13)
            cnot16<0,2>(v);                                // CN(13,0)
            if (li < 3) {
                #pragma unroll
                for (int r = 0; r < 8; ++r) {
                    s[sb0 ^ slotf(rmask3<0,1,13>(r))] = v[r];
                    s[sb1 ^ slotf(rmask3<0,1,13>(r))] = v[r + 8];
                }
            } else {
                const float mA = meas[0], mB = meas[1], mP = meas[2], mQ = meas[3];
                #pragma unroll
                for (int rr = 0; rr < 8; ++rr) {
                    const int r = (rr & 3) | ((rr >> 2) << 3);   // 0..3, 8..11
                    v2f a0 = v[r], a1 = v[r | 4];          // b13=0 / b13=1
                    float n0 = a0.x*a0.x + a0.y*a0.y;
                    float n1 = a1.x*a1.x + a1.y*a1.y;
                    float u  = a0.x*a1.x + a0.y*a1.y;      // Re(conj(a0) a1)
                    float vv = a0.x*a1.y - a0.y*a1.x;      // Im(conj(a0) a1)
                    local += mA*n0 + mB*n1 + 2.f*(mP*u - mQ*vv);
                }
            }
        }
        if (li < 3) __syncthreads();
    }

    #pragma unroll
    for (int off = 32; off > 0; off >>= 1) local += __shfl_down(local, off);
    const int lane = tid & 63, wid = tid >> 6;
    if (lane == 0) red[wid] = local;
    __syncthreads();
    if (tid == 0) {
        float t = 0.f;
        #pragma unroll
        for (int k = 0; k < BLK / 64; ++k) t += red[k];
        out[b] = t;
    }
}

extern "C" void kernel_launch(void* const* d_in, const int* in_sizes, int n_in,
                              void* d_out, int out_size, void* d_ws, size_t ws_size,
                              hipStream_t stream) {
    const float* xr = (const float*)d_in[0];
    const float* xi = (const float*)d_in[1];
    const float* w  = (const float*)d_in[2];
    float* out = (float*)d_out;
    const int B = out_size;  // 512
    qsim_kernel<<<B, BLK, 0, stream>>>(xr, xi, w, out);
}

// Round 16
// 109.623 us; speedup vs baseline: 1.4538x; 1.4538x over previous
//
#include <hip/hip_runtime.h>
#include <hip/hip_bf16.h>

#define NQ   14
#define DIM  16384      // 2^14
#define BLK  1024
#define WMUL 0.6324555320336759f  // sqrt(2/5)

typedef float v2f __attribute__((ext_vector_type(2)));

struct C2 { float x, y; };  // build-time only
__device__ inline C2 cmulc(C2 a, C2 b){ return C2{a.x*b.x - a.y*b.y, a.x*b.y + a.y*b.x}; }
__device__ inline C2 caddc(C2 a, C2 b){ return C2{a.x+b.x, a.y+b.y}; }
__device__ inline void mm2(const C2* a, const C2* b, C2* o) {
    o[0] = caddc(cmulc(a[0],b[0]), cmulc(a[1],b[2]));
    o[1] = caddc(cmulc(a[0],b[1]), cmulc(a[1],b[3]));
    o[2] = caddc(cmulc(a[2],b[0]), cmulc(a[3],b[2]));
    o[3] = caddc(cmulc(a[2],b[1]), cmulc(a[3],b[3]));
}
__device__ inline void build_gate(int ty, float t, C2* g) {
    float sn, cs;
    __sincosf(0.5f * t, &sn, &cs);
    if (ty == 0) {        // rx
        g[0] = C2{cs, 0.f}; g[1] = C2{0.f, -sn};
        g[2] = C2{0.f, -sn}; g[3] = C2{cs, 0.f};
    } else if (ty == 1) { // ry
        g[0] = C2{cs, 0.f}; g[1] = C2{-sn, 0.f};
        g[2] = C2{sn, 0.f}; g[3] = C2{cs, 0.f};
    } else {              // rz
        g[0] = C2{cs, -sn}; g[1] = C2{0.f, 0.f};
        g[2] = C2{0.f, 0.f}; g[3] = C2{cs, sn};
    }
}
__device__ const int TYPES[5][3] = {
    {0,1,2},  // XYZ
    {1,2,1},  // YZY
    {2,1,0},  // ZYX
    {0,2,0},  // XZX
    {1,2,1},  // YZY
};

// ---- prep kernel: 70 fused gates (packed form) + absorbed observable -> d_ws.
// Gates are batch-independent: compute ONCE, not per block. Main kernel reads
// them via wave-uniform global addresses -> s_load into SGPRs (scalar cache).
__global__ void prep_kernel(const float* __restrict__ w, v2f* __restrict__ gg) {
    const int tid = threadIdx.x;
    if (tid < 5 * NQ) {
        const int li = tid / NQ, q = tid % NQ;
        C2 M[4], G[4], T[4];
        #pragma unroll
        for (int j = 0; j < 3; ++j) {
            float t = w[3 * NQ * li + 3 * q + j] * WMUL;
            build_gate(TYPES[li][j], t, G);
            if (j == 0) { M[0]=G[0]; M[1]=G[1]; M[2]=G[2]; M[3]=G[3]; }
            else { mm2(G, M, T); M[0]=T[0]; M[1]=T[1]; M[2]=T[2]; M[3]=T[3]; }
        }
        v2f* gb = &gg[tid * 8];
        #pragma unroll
        for (int k = 0; k < 4; ++k) {
            gb[k * 2 + 0] = v2f{ M[k].x, M[k].x};
            gb[k * 2 + 1] = v2f{-M[k].y, M[k].y};
        }
        // absorbed observable M1 = M† Z M for the layer-5 qubit-0 rotation
        if (tid == 4 * NQ + 0) {
            float* mm = (float*)&gg[5 * NQ * 8];
            mm[0] = M[0].x*M[0].x + M[0].y*M[0].y - (M[2].x*M[2].x + M[2].y*M[2].y);
            mm[1] = M[1].x*M[1].x + M[1].y*M[1].y - (M[3].x*M[3].x + M[3].y*M[3].y);
            mm[2] = (M[0].x*M[1].x + M[0].y*M[1].y) - (M[2].x*M[3].x + M[2].y*M[3].y);
            mm[3] = (M[0].x*M[1].y - M[0].y*M[1].x) - (M[2].x*M[3].y - M[2].y*M[3].x);
        }
    }
}

// bank-conflict swizzle; GF(2)-LINEAR: slotf(a|b) = slotf(a)^slotf(b) for disjoint a,b
__device__ inline constexpr uint32_t slotf(uint32_t i){
    return i ^ (((i>>4) ^ (i>>8) ^ (i>>12)) & 15u);
}
template<int B> __device__ inline uint32_t ins0(uint32_t t){
    return ((t & ~((1u<<B)-1u)) << 1) | (t & ((1u<<B)-1u));
}
template<int B0,int B1,int B2> __device__ inline uint32_t expand3(uint32_t t){
    return ins0<B2>(ins0<B1>(ins0<B0>(t)));
}
template<int B0,int B1,int B2> __device__ inline constexpr uint32_t rmask3(int r){
    return ((r&1)?(1u<<B0):0u) | ((r&2)?(1u<<B1):0u) | ((r&4)?(1u<<B2):0u);
}

// packed rotation on local bit J. g = wave-uniform GLOBAL pointer: coefficients
// land in SGPRs (s_load) and feed v_pk_fma as the scalar operand.
template<int J>
__device__ inline void rot8(v2f* v, const v2f* __restrict__ g){
    const v2f a00=g[0], b00=g[1], a01=g[2], b01=g[3];
    const v2f a10=g[4], b10=g[5], a11=g[6], b11=g[7];
    #pragma unroll
    for (int r = 0; r < 8; ++r){
        if (!(r & (1 << J))) {
            v2f x0 = v[r], x1 = v[r | (1 << J)];
            v2f s0 = x0.yx, s1 = x1.yx;
            v2f y0 = a00*x0 + b00*s0 + a01*x1 + b01*s1;
            v2f y1 = a10*x0 + b10*s0 + a11*x1 + b11*s1;
            v[r] = y0; v[r | (1<<J)] = y1;
        }
    }
}
// CNOT both-in-reg: control bit C, target bit T (register renaming, free)
template<int C, int T>
__device__ inline void cnot8(v2f* v){
    #pragma unroll
    for (int r = 0; r < 8; ++r){
        if ((r & (1 << C)) && !(r & (1 << T))) {
            v2f tt = v[r]; v[r] = v[r | (1 << T)]; v[r | (1 << T)] = tt;
        }
    }
}
// CNOT with control = thread-index bit, target reg bit T: pure v_cndmask
template<int T>
__device__ inline void cnotSel(v2f* v, bool c){
    #pragma unroll
    for (int r = 0; r < 8; ++r){
        if (!(r & (1 << T))) {
            v2f lo = v[r], hi = v[r | (1 << T)];
            v[r]          = c ? hi : lo;
            v[r | (1<<T)] = c ? lo : hi;
        }
    }
}

__global__ __launch_bounds__(BLK) void qsim_kernel(
        const float* __restrict__ xr, const float* __restrict__ xi,
        const v2f* __restrict__ gg, float* __restrict__ out) {
    __shared__ v2f s[DIM];            // 128 KiB statevector (swizzled layout)
    __shared__ float red[BLK / 64];

    const int b   = blockIdx.x;
    const uint32_t tid = threadIdx.x;

    const float* xrb = xr + (size_t)b * DIM;
    const float* xib = xi + (size_t)b * DIM;

    // qubit q <-> bit (13-q).  coefficients: uniform global -> SGPR
    #define GMP(li, q) (&gg[((li) * NQ + (q)) * 8])

    // One pass: 2 sequential slabs (live state = v2f v[8] = 16 VGPRs).
    #define PASS(B0, B1, B2, ...)                                                  \
        _Pragma("unroll 1")                                                        \
        for (uint32_t sl = 0; sl < 2; ++sl) {                                      \
            const uint32_t t  = tid + sl * BLK;                                    \
            const uint32_t sb = slotf(expand3<B0,B1,B2>(t));                       \
            v2f v[8];                                                              \
            _Pragma("unroll")                                                      \
            for (int r = 0; r < 8; ++r)                                            \
                v[r] = s[sb ^ slotf(rmask3<B0,B1,B2>(r))];                         \
            __VA_ARGS__                                                            \
            _Pragma("unroll")                                                      \
            for (int r = 0; r < 8; ++r)                                            \
                s[sb ^ slotf(rmask3<B0,B1,B2>(r))] = v[r];                         \
        }                                                                          \
        __syncthreads();

    float local = 0.f;

    // ---- 4 ring layers, 5 non-overlapping windows each; L5 absorbed in meas ----
    // A(11,12,13): rot q0,q1,q2 + CN(0,1),(1,2)
    // B(8,9,10):   rot q3,q4,q5 + CN(2,3)[sel ctl=t8] + CN(3,4),(4,5)
    // C(5,6,7):    rot q6,q7,q8 + CN(5,6)[sel ctl=t5] + CN(6,7),(7,8)
    // D(2,3,4):    rot q9,q10,q11 + CN(8,9)[sel ctl=t2] + CN(9,10),(10,11)
    // E(0,1,13):   rot q12,q13 + CN(11,12)[sel ctl=t0] + CN(12,13),(13,0)
    //              (li==3: fuse M1 quadratic form on b13 = L2 pairs, no scatter)
    #pragma unroll 1
    for (int li = 0; li < 4; ++li) {
        // ---- A (11,12,13) ----
        #pragma unroll 1
        for (uint32_t sl = 0; sl < 2; ++sl) {
            const uint32_t t = tid + sl * BLK;
            v2f v[8];
            if (li == 0) {
                #pragma unroll
                for (int r = 0; r < 8; ++r) {
                    uint32_t i = t | ((uint32_t)r << 11);   // expand3<11,12,13>(t)=t
                    v[r] = v2f{xrb[i], xib[i]};
                }
            } else {
                const uint32_t sb = slotf(expand3<11,12,13>(t));
                #pragma unroll
                for (int r = 0; r < 8; ++r)
                    v[r] = s[sb ^ slotf(rmask3<11,12,13>(r))];
            }
            rot8<2>(v, GMP(li,0)); rot8<1>(v, GMP(li,1)); rot8<0>(v, GMP(li,2));
            cnot8<2,1>(v); cnot8<1,0>(v);                  // CN(0,1),(1,2)
            const uint32_t sb = slotf(expand3<11,12,13>(t));
            #pragma unroll
            for (int r = 0; r < 8; ++r)
                s[sb ^ slotf(rmask3<11,12,13>(r))] = v[r];
        }
        __syncthreads();

        // ---- B (8,9,10): rot q3(b10),q4(b9),q5(b8) ----
        PASS(8,9,10,
            rot8<2>(v, GMP(li,3)); rot8<1>(v, GMP(li,4)); rot8<0>(v, GMP(li,5));
            cnotSel<2>(v, (t >> 8) & 1u);                  // CN(2,3): ctl q2=b11
            cnot8<2,1>(v); cnot8<1,0>(v);                  // CN(3,4),(4,5)
        )
        // ---- C (5,6,7): rot q6(b7),q7(b6),q8(b5) ----
        PASS(5,6,7,
            rot8<2>(v, GMP(li,6)); rot8<1>(v, GMP(li,7)); rot8<0>(v, GMP(li,8));
            cnotSel<2>(v, (t >> 5) & 1u);                  // CN(5,6): ctl q5=b8
            cnot8<2,1>(v); cnot8<1,0>(v);                  // CN(6,7),(7,8)
        )
        // ---- D (2,3,4): rot q9(b4),q10(b3),q11(b2) ----
        PASS(2,3,4,
            rot8<2>(v, GMP(li,9)); rot8<1>(v, GMP(li,10)); rot8<0>(v, GMP(li,11));
            cnotSel<2>(v, (t >> 2) & 1u);                  // CN(8,9): ctl q8=b5
            cnot8<2,1>(v); cnot8<1,0>(v);                  // CN(9,10),(10,11)
        )
        // ---- E (0,1,13): rot q12(b1=L1),q13(b0=L0) ----
        #pragma unroll 1
        for (uint32_t sl = 0; sl < 2; ++sl) {
            const uint32_t t  = tid + sl * BLK;
            const uint32_t sb = slotf(expand3<0,1,13>(t));
            v2f v[8];
            #pragma unroll
            for (int r = 0; r < 8; ++r)
                v[r] = s[sb ^ slotf(rmask3<0,1,13>(r))];
            rot8<1>(v, GMP(li,12)); rot8<0>(v, GMP(li,13));
            cnotSel<1>(v, t & 1u);                         // CN(11,12): ctl q11=b2
            cnot8<1,0>(v);                                 // CN(12,13)
            cnot8<0,2>(v);                                 // CN(13,0)
            if (li < 3) {
                #pragma unroll
                for (int r = 0; r < 8; ++r)
                    s[sb ^ slotf(rmask3<0,1,13>(r))] = v[r];
            } else {
                const float* mm = (const float*)&gg[5 * NQ * 8];
                const float mA = mm[0], mB = mm[1], mP = mm[2], mQ = mm[3];
                #pragma unroll
                for (int r = 0; r < 4; ++r) {
                    v2f a0 = v[r], a1 = v[r | 4];          // b13=0 / b13=1
                    float n0 = a0.x*a0.x + a0.y*a0.y;
                    float n1 = a1.x*a1.x + a1.y*a1.y;
                    float u  = a0.x*a1.x + a0.y*a1.y;      // Re(conj(a0) a1)
                    float vv = a0.x*a1.y - a0.y*a1.x;      // Im(conj(a0) a1)
                    local += mA*n0 + mB*n1 + 2.f*(mP*u - mQ*vv);
                }
            }
        }
        if (li < 3) __syncthreads();
    }

    #pragma unroll
    for (int off = 32; off > 0; off >>= 1) local += __shfl_down(local, off);
    const int lane = tid & 63, wid = tid >> 6;
    if (lane == 0) red[wid] = local;
    __syncthreads();
    if (tid == 0) {
        float t = 0.f;
        #pragma unroll
        for (int k = 0; k < BLK / 64; ++k) t += red[k];
        out[b] = t;
    }
}

extern "C" void kernel_launch(void* const* d_in, const int* in_sizes, int n_in,
                              void* d_out, int out_size, void* d_ws, size_t ws_size,
                              hipStream_t stream) {
    const float* xr = (const float*)d_in[0];
    const float* xi = (const float*)d_in[1];
    const float* w  = (const float*)d_in[2];
    float* out = (float*)d_out;
    v2f* gg = (v2f*)d_ws;     // 70 gates x 8 v2f + 4 floats meas = 4496 B
    const int B = out_size;   // 512
    prep_kernel<<<1, 128, 0, stream>>>(w, gg);
    qsim_kernel<<<B, BLK, 0, stream>>>(xr, xi, gg, out);
}